// Round 3
// baseline (295.382 us; speedup 1.0000x reference)
//
#include <hip/hip_runtime.h>
#include <math.h>

#define BATCH 8
#define T 2048
#define N 256        // STATE
#define INF 128      // IN
#define OUTF 128     // OUT
#define L 32         // chunk length (power of 2)
#define LOG2L 5
#define NC (T / L)   // 64 chunks
#define TJ 8         // time tile in K1
#define K4 (INF / 4) // 32 float4 groups over input features
#define TT 16        // time tile in K3 (one block = 16 timesteps x 128 outputs)
#define SXS 260      // padded LDS row stride for sx (kills 4-way t-group bank alias)
#define SUS 132      // padded LDS row stride for su2

// ---------------- K0: stabilize A and build power table A^1..A^L ----------------
__global__ __launch_bounds__(N) void k0_powers(const float* __restrict__ Are,
                                               const float* __restrict__ Aim,
                                               float2* __restrict__ Apow) {
    int n = threadIdx.x;
    float ar = Are[n], ai = Aim[n];
    float m = ar * ar + ai * ai + 1.0f;
    float inv = 1.0f / sqrtf(m);
    ar *= inv; ai *= inv;
    float pr = ar, pi = ai;
    for (int j = 0; j < L; ++j) {
        Apow[j * N + n] = make_float2(pr, pi);   // A^(j+1)
        float nr = pr * ar - pi * ai;
        float ni = pr * ai + pi * ar;
        pr = nr; pi = ni;
    }
}

// ---------------- K1: fused u@B + chunk-local scan ----------------
// grid (NC, BATCH), block 256 (one thread per state n)
__global__ __launch_bounds__(256) void k1_scan(const float* __restrict__ u,
                                               const float* __restrict__ Bre,
                                               const float* __restrict__ Bim,
                                               const float2* __restrict__ Apow,
                                               float2* __restrict__ xbuf,
                                               float2* __restrict__ finals) {
    __shared__ float4 su4[L * K4];   // 32*32*16B = 16 KB
    int c = blockIdx.x, b = blockIdx.y;
    int tid = threadIdx.x;
    const float4* ub4 = (const float4*)(u + ((size_t)b * T + (size_t)c * L) * INF);
    for (int idx = tid; idx < L * K4; idx += 256) su4[idx] = ub4[idx];
    __syncthreads();

    int n = tid;
    float2 a = Apow[n];  // A^1 (stabilized A)
    float xr = 0.f, xi = 0.f;
    float2* xout = xbuf + ((size_t)b * T + (size_t)c * L) * N + n;

    for (int jt = 0; jt < L; jt += TJ) {
        float ubr[TJ], ubi[TJ];
#pragma unroll
        for (int jj = 0; jj < TJ; ++jj) { ubr[jj] = 0.f; ubi[jj] = 0.f; }
        for (int k4 = 0; k4 < K4; ++k4) {
            float4 uu[TJ];
#pragma unroll
            for (int jj = 0; jj < TJ; ++jj) uu[jj] = su4[(jt + jj) * K4 + k4];  // wave-uniform b128 broadcast
#pragma unroll
            for (int kk = 0; kk < 4; ++kk) {
                int k = k4 * 4 + kk;
                float br = Bre[k * N + n];
                float bi = Bim[k * N + n];
#pragma unroll
                for (int jj = 0; jj < TJ; ++jj) {
                    float uv = (kk == 0) ? uu[jj].x : (kk == 1) ? uu[jj].y
                             : (kk == 2) ? uu[jj].z : uu[jj].w;
                    ubr[jj] = fmaf(uv, br, ubr[jj]);
                    ubi[jj] = fmaf(uv, bi, ubi[jj]);
                }
            }
        }
#pragma unroll
        for (int jj = 0; jj < TJ; ++jj) {
            float nr = a.x * xr - a.y * xi + ubr[jj];
            float ni = a.x * xi + a.y * xr + ubi[jj];
            xr = nr; xi = ni;
            xout[(size_t)(jt + jj) * N] = make_float2(xr, xi);
        }
    }
    finals[((size_t)b * NC + c) * N + n] = make_float2(xr, xi);
}

// ---------------- K2: carry propagation across chunks + x_last output ----------------
// grid BATCH, block 256
// tail_mode: 0 = none, 1 = real-only (out has B*N floats), 2 = interleaved re/im
__global__ __launch_bounds__(256) void k2_carry(const float* __restrict__ x0re,
                                                const float* __restrict__ x0im,
                                                const float2* __restrict__ Apow,
                                                const float2* __restrict__ finals,
                                                float2* __restrict__ prevs,
                                                float* __restrict__ out_tail,
                                                int tail_mode) {
    int b = blockIdx.x, n = threadIdx.x;
    float pr = x0re[b * N + n], pi = x0im[b * N + n];   // x[-1] = x0
    float2 aL = Apow[(L - 1) * N + n];                   // A^L
#pragma unroll 8
    for (int c = 0; c < NC; ++c) {
        prevs[((size_t)b * NC + c) * N + n] = make_float2(pr, pi);
        float2 f = finals[((size_t)b * NC + c) * N + n];
        float nr = f.x + aL.x * pr - aL.y * pi;
        float ni = f.y + aL.x * pi + aL.y * pr;
        pr = nr; pi = ni;
    }
    if (tail_mode == 2) {
        out_tail[(b * N + n) * 2 + 0] = pr;
        out_tail[(b * N + n) * 2 + 1] = pi;
    } else if (tail_mode == 1) {
        out_tail[b * N + n] = pr;
    }
}

// ---------------- K3: correction + y = Re(x@C) + u@D + b ----------------
// grid (T/TT, BATCH), block 256; thread = (timestep tg = tid>>4, outputs og*8..og*8+7)
__global__ __launch_bounds__(256) void k3_out(const float2* __restrict__ xbuf,
                                              const float2* __restrict__ Apow,
                                              const float2* __restrict__ prevs,
                                              const float* __restrict__ u,
                                              const float* __restrict__ Cre,
                                              const float* __restrict__ Cim,
                                              const float* __restrict__ D,
                                              const float* __restrict__ bias,
                                              float* __restrict__ y) {
    __shared__ float sxr[TT][SXS];
    __shared__ float sxi[TT][SXS];
    __shared__ float su2[TT][SUS];
    int b = blockIdx.y;
    int t0 = blockIdx.x * TT;
    int tid = threadIdx.x;

    // load x-tile, apply carry correction x = xl + A^(j+1) * prev
    for (int idx = tid; idx < TT * N; idx += 256) {
        int tt = idx >> 8;          // N = 256
        int n = idx & (N - 1);
        int t = t0 + tt;
        int j = t & (L - 1);
        int c = t >> LOG2L;
        float2 xv = xbuf[((size_t)b * T + t) * N + n];
        float2 p = Apow[j * N + n];
        float2 v = prevs[((size_t)b * NC + c) * N + n];
        sxr[tt][n] = xv.x + p.x * v.x - p.y * v.y;
        sxi[tt][n] = xv.y + p.x * v.y + p.y * v.x;
    }
    for (int idx = tid; idx < TT * INF; idx += 256) {
        int tt = idx >> 7;          // INF = 128
        int k = idx & (INF - 1);
        su2[tt][k] = u[((size_t)b * T + t0 + tt) * INF + k];
    }
    __syncthreads();

    int tg = tid >> 4;          // 0..15 timestep within tile
    int og = tid & 15;          // output group: o = og*8 .. og*8+7
    const float4* Cre4 = (const float4*)Cre;
    const float4* Cim4 = (const float4*)Cim;
    const float4* D4   = (const float4*)D;
    const float4* b4   = (const float4*)bias;

    float4 acc0 = b4[og * 2 + 0];
    float4 acc1 = b4[og * 2 + 1];

#pragma unroll 2
    for (int n = 0; n < N; ++n) {
        float xr = sxr[tg][n];              // broadcast within 16-lane group
        float xi = sxi[tg][n];
        float4 cr0 = Cre4[n * (OUTF / 4) + og * 2 + 0];
        float4 cr1 = Cre4[n * (OUTF / 4) + og * 2 + 1];
        float4 ci0 = Cim4[n * (OUTF / 4) + og * 2 + 0];
        float4 ci1 = Cim4[n * (OUTF / 4) + og * 2 + 1];
        acc0.x = fmaf(xr, cr0.x, fmaf(-xi, ci0.x, acc0.x));
        acc0.y = fmaf(xr, cr0.y, fmaf(-xi, ci0.y, acc0.y));
        acc0.z = fmaf(xr, cr0.z, fmaf(-xi, ci0.z, acc0.z));
        acc0.w = fmaf(xr, cr0.w, fmaf(-xi, ci0.w, acc0.w));
        acc1.x = fmaf(xr, cr1.x, fmaf(-xi, ci1.x, acc1.x));
        acc1.y = fmaf(xr, cr1.y, fmaf(-xi, ci1.y, acc1.y));
        acc1.z = fmaf(xr, cr1.z, fmaf(-xi, ci1.z, acc1.z));
        acc1.w = fmaf(xr, cr1.w, fmaf(-xi, ci1.w, acc1.w));
    }
#pragma unroll 2
    for (int k = 0; k < INF; ++k) {
        float uv = su2[tg][k];
        float4 d0 = D4[k * (OUTF / 4) + og * 2 + 0];
        float4 d1 = D4[k * (OUTF / 4) + og * 2 + 1];
        acc0.x = fmaf(uv, d0.x, acc0.x);
        acc0.y = fmaf(uv, d0.y, acc0.y);
        acc0.z = fmaf(uv, d0.z, acc0.z);
        acc0.w = fmaf(uv, d0.w, acc0.w);
        acc1.x = fmaf(uv, d1.x, acc1.x);
        acc1.y = fmaf(uv, d1.y, acc1.y);
        acc1.z = fmaf(uv, d1.z, acc1.z);
        acc1.w = fmaf(uv, d1.w, acc1.w);
    }
    float4* yv = (float4*)(y + ((size_t)b * T + t0 + tg) * OUTF);
    yv[og * 2 + 0] = acc0;
    yv[og * 2 + 1] = acc1;
}

extern "C" void kernel_launch(void* const* d_in, const int* in_sizes, int n_in,
                              void* d_out, int out_size, void* d_ws, size_t ws_size,
                              hipStream_t stream) {
    const float* u    = (const float*)d_in[0];
    const float* x0re = (const float*)d_in[1];
    const float* x0im = (const float*)d_in[2];
    const float* Are  = (const float*)d_in[3];
    const float* Aim  = (const float*)d_in[4];
    const float* Bre  = (const float*)d_in[5];
    const float* Bim  = (const float*)d_in[6];
    const float* Cre  = (const float*)d_in[7];
    const float* Cim  = (const float*)d_in[8];
    const float* D    = (const float*)d_in[9];
    const float* bias = (const float*)d_in[10];
    float* y = (float*)d_out;

    char* ws = (char*)d_ws;
    float2* Apow   = (float2*)ws;                                   // 64 KB
    char* p = ws + (size_t)L * N * sizeof(float2);
    float2* xbuf   = (float2*)p;                                    // 33.5 MB
    p += (size_t)BATCH * T * N * sizeof(float2);
    float2* finals = (float2*)p;                                    // 1 MB
    p += (size_t)BATCH * NC * N * sizeof(float2);
    float2* prevs  = (float2*)p;                                    // 1 MB

    const int ysz = BATCH * T * OUTF;
    const int tail_elems = out_size - ysz;
    int tail_mode = (tail_elems >= BATCH * N * 2) ? 2
                  : (tail_elems >= BATCH * N) ? 1 : 0;
    float* tail = y + ysz;

    k0_powers<<<1, N, 0, stream>>>(Are, Aim, Apow);
    k1_scan<<<dim3(NC, BATCH), 256, 0, stream>>>(u, Bre, Bim, Apow, xbuf, finals);
    k2_carry<<<BATCH, 256, 0, stream>>>(x0re, x0im, Apow, finals, prevs, tail, tail_mode);
    k3_out<<<dim3(T / TT, BATCH), 256, 0, stream>>>(xbuf, Apow, prevs, u, Cre, Cim, D, bias, y);
}

// Round 4
// 215.623 us; speedup vs baseline: 1.3699x; 1.3699x over previous
//
#include <hip/hip_runtime.h>
#include <math.h>

#define BATCH 8
#define T 2048
#define N 256        // STATE
#define INF 128      // IN
#define OUTF 128     // OUT
#define L 32         // chunk length (power of 2)
#define LOG2L 5
#define NC (T / L)   // 64 chunks
#define TJ 8         // time tile in K1
#define K4 (INF / 4) // 32 float4 groups over input features
#define TT3 16       // time tile in K3
#define SUSTRIDE 20  // padded float stride for su rows (80B: 16B-aligned, 4-way max on writes)

// ---------------- K0: stabilize A and build power table A^1..A^L ----------------
__global__ __launch_bounds__(N) void k0_powers(const float* __restrict__ Are,
                                               const float* __restrict__ Aim,
                                               float2* __restrict__ Apow) {
    int n = threadIdx.x;
    float ar = Are[n], ai = Aim[n];
    float m = ar * ar + ai * ai + 1.0f;
    float inv = 1.0f / sqrtf(m);
    ar *= inv; ai *= inv;
    float pr = ar, pi = ai;
    for (int j = 0; j < L; ++j) {
        Apow[j * N + n] = make_float2(pr, pi);   // A^(j+1)
        float nr = pr * ar - pi * ai;
        float ni = pr * ai + pi * ar;
        pr = nr; pi = ni;
    }
}

// ---------------- K1: fused u@B + chunk-local scan ----------------
// grid (NC, BATCH), block 256 (one thread per state n)
__global__ __launch_bounds__(256) void k1_scan(const float* __restrict__ u,
                                               const float* __restrict__ Bre,
                                               const float* __restrict__ Bim,
                                               const float2* __restrict__ Apow,
                                               float2* __restrict__ xbuf,
                                               float2* __restrict__ finals) {
    __shared__ float4 su4[L * K4];   // 32*32*16B = 16 KB
    int c = blockIdx.x, b = blockIdx.y;
    int tid = threadIdx.x;
    const float4* ub4 = (const float4*)(u + ((size_t)b * T + (size_t)c * L) * INF);
    for (int idx = tid; idx < L * K4; idx += 256) su4[idx] = ub4[idx];
    __syncthreads();

    int n = tid;
    float2 a = Apow[n];  // A^1 (stabilized A)
    float xr = 0.f, xi = 0.f;
    float2* xout = xbuf + ((size_t)b * T + (size_t)c * L) * N + n;

    for (int jt = 0; jt < L; jt += TJ) {
        float ubr[TJ], ubi[TJ];
#pragma unroll
        for (int jj = 0; jj < TJ; ++jj) { ubr[jj] = 0.f; ubi[jj] = 0.f; }
        for (int k4 = 0; k4 < K4; ++k4) {
            float4 uu[TJ];
#pragma unroll
            for (int jj = 0; jj < TJ; ++jj) uu[jj] = su4[(jt + jj) * K4 + k4];  // wave-uniform b128 broadcast
#pragma unroll
            for (int kk = 0; kk < 4; ++kk) {
                int k = k4 * 4 + kk;
                float br = Bre[k * N + n];
                float bi = Bim[k * N + n];
#pragma unroll
                for (int jj = 0; jj < TJ; ++jj) {
                    float uv = (kk == 0) ? uu[jj].x : (kk == 1) ? uu[jj].y
                             : (kk == 2) ? uu[jj].z : uu[jj].w;
                    ubr[jj] = fmaf(uv, br, ubr[jj]);
                    ubi[jj] = fmaf(uv, bi, ubi[jj]);
                }
            }
        }
#pragma unroll
        for (int jj = 0; jj < TJ; ++jj) {
            float nr = a.x * xr - a.y * xi + ubr[jj];
            float ni = a.x * xi + a.y * xr + ubi[jj];
            xr = nr; xi = ni;
            xout[(size_t)(jt + jj) * N] = make_float2(xr, xi);
        }
    }
    finals[((size_t)b * NC + c) * N + n] = make_float2(xr, xi);
}

// ---------------- K2: carry propagation across chunks + x_last output ----------------
__global__ __launch_bounds__(256) void k2_carry(const float* __restrict__ x0re,
                                                const float* __restrict__ x0im,
                                                const float2* __restrict__ Apow,
                                                const float2* __restrict__ finals,
                                                float2* __restrict__ prevs,
                                                float* __restrict__ out_tail,
                                                int tail_mode) {
    int b = blockIdx.x, n = threadIdx.x;
    float pr = x0re[b * N + n], pi = x0im[b * N + n];   // x[-1] = x0
    float2 aL = Apow[(L - 1) * N + n];                   // A^L
#pragma unroll 8
    for (int c = 0; c < NC; ++c) {
        prevs[((size_t)b * NC + c) * N + n] = make_float2(pr, pi);
        float2 f = finals[((size_t)b * NC + c) * N + n];
        float nr = f.x + aL.x * pr - aL.y * pi;
        float ni = f.y + aL.x * pi + aL.y * pr;
        pr = nr; pi = ni;
    }
    if (tail_mode == 2) {
        out_tail[(b * N + n) * 2 + 0] = pr;
        out_tail[(b * N + n) * 2 + 1] = pi;
    } else if (tail_mode == 1) {
        out_tail[b * N + n] = pr;
    }
}

// ---------------- K3: correction + y = Re(x@C) + u@D + b ----------------
// grid (T/TT3, BATCH), block 128 = 64 o-pairs x 2 t-groups (8 timesteps each)
__global__ __launch_bounds__(128) void k3_out(const float2* __restrict__ xbuf,
                                              const float2* __restrict__ Apow,
                                              const float2* __restrict__ prevs,
                                              const float* __restrict__ u,
                                              const float* __restrict__ Cre,
                                              const float* __restrict__ Cim,
                                              const float* __restrict__ D,
                                              const float* __restrict__ bias,
                                              float* __restrict__ y) {
    __shared__ float2 sx[TT3][N];                        // 32 KB, (xr,xi) packed
    __shared__ __align__(16) float su[INF * SUSTRIDE];   // 10.25 KB, u transposed [k][t]
    int b = blockIdx.y;
    int t0 = blockIdx.x * TT3;
    int tid = threadIdx.x;

    // stage x-tile with carry correction x = xl + A^(j+1) * prev (coalesced b64)
#pragma unroll
    for (int i = 0; i < (TT3 * N) / 128; ++i) {
        int idx = tid + i * 128;
        int tt = idx >> 8;          // N = 256
        int n = idx & (N - 1);
        int t = t0 + tt;
        int j = t & (L - 1);
        int c = t >> LOG2L;
        float2 xv = xbuf[((size_t)b * T + t) * N + n];
        float2 p = Apow[j * N + n];
        float2 v = prevs[((size_t)b * NC + c) * N + n];
        sx[tt][n] = make_float2(xv.x + p.x * v.x - p.y * v.y,
                                xv.y + p.x * v.y + p.y * v.x);
    }
    // stage u transposed [k][t]
#pragma unroll
    for (int i = 0; i < (TT3 * INF) / 128; ++i) {
        int idx = tid + i * 128;
        int tt = idx >> 7;          // INF = 128
        int k = idx & (INF - 1);
        su[k * SUSTRIDE + tt] = u[((size_t)b * T + t0 + tt) * INF + k];
    }
    __syncthreads();

    int og = tid & 63;              // output pair: o = og*2, og*2+1
    int tg = tid >> 6;              // 0..1, wave-uniform: 8 timesteps each
    const float2* C_re = (const float2*)Cre;
    const float2* C_im = (const float2*)Cim;
    const float2* D2   = (const float2*)D;
    const float2* bi2  = (const float2*)bias;

    float2 bv = bi2[og];
    float2 acc[8];
#pragma unroll
    for (int r = 0; r < 8; ++r) acc[r] = bv;

    // C-part: per n: 2 coalesced global b64 (C) + 8 LDS b64 broadcasts (x) + 32 fmaf
#pragma unroll 2
    for (int n = 0; n < N; ++n) {
        float2 cre = C_re[n * (OUTF / 2) + og];
        float2 cim = C_im[n * (OUTF / 2) + og];
#pragma unroll
        for (int r = 0; r < 8; ++r) {
            float2 xv = sx[tg * 8 + r][n];     // all-lane broadcast
            acc[r].x = fmaf(xv.x, cre.x, fmaf(-xv.y, cim.x, acc[r].x));
            acc[r].y = fmaf(xv.x, cre.y, fmaf(-xv.y, cim.y, acc[r].y));
        }
    }
    // D-part: per k: 1 global b64 (D) + 2 LDS b128 broadcasts (u) + 16 fmaf
#pragma unroll 2
    for (int k = 0; k < INF; ++k) {
        float2 dv = D2[k * (OUTF / 2) + og];
        const float4* s4 = (const float4*)&su[k * SUSTRIDE + tg * 8];
        float4 ua = s4[0];
        float4 ub = s4[1];
        acc[0].x = fmaf(ua.x, dv.x, acc[0].x);  acc[0].y = fmaf(ua.x, dv.y, acc[0].y);
        acc[1].x = fmaf(ua.y, dv.x, acc[1].x);  acc[1].y = fmaf(ua.y, dv.y, acc[1].y);
        acc[2].x = fmaf(ua.z, dv.x, acc[2].x);  acc[2].y = fmaf(ua.z, dv.y, acc[2].y);
        acc[3].x = fmaf(ua.w, dv.x, acc[3].x);  acc[3].y = fmaf(ua.w, dv.y, acc[3].y);
        acc[4].x = fmaf(ub.x, dv.x, acc[4].x);  acc[4].y = fmaf(ub.x, dv.y, acc[4].y);
        acc[5].x = fmaf(ub.y, dv.x, acc[5].x);  acc[5].y = fmaf(ub.y, dv.y, acc[5].y);
        acc[6].x = fmaf(ub.z, dv.x, acc[6].x);  acc[6].y = fmaf(ub.z, dv.y, acc[6].y);
        acc[7].x = fmaf(ub.w, dv.x, acc[7].x);  acc[7].y = fmaf(ub.w, dv.y, acc[7].y);
    }
#pragma unroll
    for (int r = 0; r < 8; ++r) {
        *(float2*)&y[((size_t)b * T + t0 + tg * 8 + r) * OUTF + og * 2] = acc[r];
    }
}

extern "C" void kernel_launch(void* const* d_in, const int* in_sizes, int n_in,
                              void* d_out, int out_size, void* d_ws, size_t ws_size,
                              hipStream_t stream) {
    const float* u    = (const float*)d_in[0];
    const float* x0re = (const float*)d_in[1];
    const float* x0im = (const float*)d_in[2];
    const float* Are  = (const float*)d_in[3];
    const float* Aim  = (const float*)d_in[4];
    const float* Bre  = (const float*)d_in[5];
    const float* Bim  = (const float*)d_in[6];
    const float* Cre  = (const float*)d_in[7];
    const float* Cim  = (const float*)d_in[8];
    const float* D    = (const float*)d_in[9];
    const float* bias = (const float*)d_in[10];
    float* y = (float*)d_out;

    char* ws = (char*)d_ws;
    float2* Apow   = (float2*)ws;                                   // 64 KB
    char* p = ws + (size_t)L * N * sizeof(float2);
    float2* xbuf   = (float2*)p;                                    // 33.5 MB
    p += (size_t)BATCH * T * N * sizeof(float2);
    float2* finals = (float2*)p;                                    // 1 MB
    p += (size_t)BATCH * NC * N * sizeof(float2);
    float2* prevs  = (float2*)p;                                    // 1 MB

    const int ysz = BATCH * T * OUTF;
    const int tail_elems = out_size - ysz;
    int tail_mode = (tail_elems >= BATCH * N * 2) ? 2
                  : (tail_elems >= BATCH * N) ? 1 : 0;
    float* tail = y + ysz;

    k0_powers<<<1, N, 0, stream>>>(Are, Aim, Apow);
    k1_scan<<<dim3(NC, BATCH), 256, 0, stream>>>(u, Bre, Bim, Apow, xbuf, finals);
    k2_carry<<<BATCH, 256, 0, stream>>>(x0re, x0im, Apow, finals, prevs, tail, tail_mode);
    k3_out<<<dim3(T / TT3, BATCH), 128, 0, stream>>>(xbuf, Apow, prevs, u, Cre, Cim, D, bias, y);
}

// Round 5
// 142.625 us; speedup vs baseline: 2.0710x; 1.5118x over previous
//
#include <hip/hip_runtime.h>
#include <math.h>

#define BATCH 8
#define T 2048
#define N 256        // STATE
#define INF 128      // IN
#define OUTF 128     // OUT
#define L 16         // chunk length
#define LOG2L 4
#define NC (T / L)   // 128 chunks
#define TJ 8         // time tile in K1
#define TT3 16       // time tile in K3
#define SUP 20       // padded float stride for su rows in K3 (80 B, 16B-aligned)

// ---------------- K0: stabilize A and build power table A^1..A^L ----------------
__global__ __launch_bounds__(N) void k0_powers(const float* __restrict__ Are,
                                               const float* __restrict__ Aim,
                                               float2* __restrict__ Apow) {
    int n = threadIdx.x;
    float ar = Are[n], ai = Aim[n];
    float m = ar * ar + ai * ai + 1.0f;
    float inv = 1.0f / sqrtf(m);
    ar *= inv; ai *= inv;
    float pr = ar, pi = ai;
    for (int j = 0; j < L; ++j) {
        Apow[j * N + n] = make_float2(pr, pi);   // A^(j+1)
        float nr = pr * ar - pi * ai;
        float ni = pr * ai + pi * ar;
        pr = nr; pi = ni;
    }
}

// ---------------- K1: fused u@B + chunk-local scan ----------------
// grid (NC, BATCH), block 256 (one thread per state n); 1024 blocks = 4/CU
__global__ __launch_bounds__(256, 4) void k1_scan(const float* __restrict__ u,
                                                  const float* __restrict__ Bre,
                                                  const float* __restrict__ Bim,
                                                  const float2* __restrict__ Apow,
                                                  float2* __restrict__ xbuf,
                                                  float2* __restrict__ finals) {
    __shared__ float su[L * INF];   // 16*128*4 = 8 KB
    int c = blockIdx.x, b = blockIdx.y;
    int tid = threadIdx.x;
    const float4* ub4 = (const float4*)(u + ((size_t)b * T + (size_t)c * L) * INF);
    float4* su4 = (float4*)su;
    for (int idx = tid; idx < (L * INF) / 4; idx += 256) su4[idx] = ub4[idx];
    __syncthreads();

    int n = tid;
    float2 a = Apow[n];  // A^1 (stabilized)
    float xr = 0.f, xi = 0.f;
    float2* xout = xbuf + ((size_t)b * T + (size_t)c * L) * N + n;

    for (int jt = 0; jt < L; jt += TJ) {
        float ubr[TJ], ubi[TJ];
#pragma unroll
        for (int jj = 0; jj < TJ; ++jj) { ubr[jj] = 0.f; ubi[jj] = 0.f; }
#pragma unroll 2
        for (int k = 0; k < INF; k += 2) {
            float br0 = Bre[k * N + n];
            float bi0 = Bim[k * N + n];
            float br1 = Bre[(k + 1) * N + n];
            float bi1 = Bim[(k + 1) * N + n];
#pragma unroll
            for (int jj = 0; jj < TJ; ++jj) {
                float2 uv = *(const float2*)&su[(jt + jj) * INF + k];  // broadcast b64
                ubr[jj] = fmaf(uv.x, br0, ubr[jj]);
                ubi[jj] = fmaf(uv.x, bi0, ubi[jj]);
                ubr[jj] = fmaf(uv.y, br1, ubr[jj]);
                ubi[jj] = fmaf(uv.y, bi1, ubi[jj]);
            }
        }
#pragma unroll
        for (int jj = 0; jj < TJ; ++jj) {
            float nr = a.x * xr - a.y * xi + ubr[jj];
            float ni = a.x * xi + a.y * xr + ubi[jj];
            xr = nr; xi = ni;
            xout[(size_t)(jt + jj) * N] = make_float2(xr, xi);
        }
    }
    finals[((size_t)b * NC + c) * N + n] = make_float2(xr, xi);
}

// ---------------- K2: carry propagation (in-place: finals -> prevs) + x_last ----------------
// grid BATCH, block 256
__global__ __launch_bounds__(256) void k2_carry(const float* __restrict__ x0re,
                                                const float* __restrict__ x0im,
                                                const float2* __restrict__ Apow,
                                                float2* __restrict__ carr,   // in: finals, out: prevs
                                                float* __restrict__ out_tail,
                                                int tail_mode) {
    int b = blockIdx.x, n = threadIdx.x;
    float pr = x0re[b * N + n], pi = x0im[b * N + n];   // x[-1] = x0
    float2 aL = Apow[(L - 1) * N + n];                   // A^L
#pragma unroll 8
    for (int c = 0; c < NC; ++c) {
        size_t off = ((size_t)b * NC + c) * N + n;
        float2 f = carr[off];                 // read chunk-final BEFORE overwrite
        carr[off] = make_float2(pr, pi);      // write carry-in for chunk c
        float nr = f.x + aL.x * pr - aL.y * pi;
        float ni = f.y + aL.x * pi + aL.y * pr;
        pr = nr; pi = ni;
    }
    if (tail_mode == 2) {
        out_tail[(b * N + n) * 2 + 0] = pr;
        out_tail[(b * N + n) * 2 + 1] = pi;
    } else if (tail_mode == 1) {
        out_tail[b * N + n] = pr;
    }
}

// ---------------- K3: correction + y = Re(x@C) + u@D + b ----------------
// grid (T/TT3, BATCH), block 256 = 64 o-pairs x 4 t-groups (4 timesteps each)
__global__ __launch_bounds__(256, 3) void k3_out(const float2* __restrict__ xbuf,
                                                 const float2* __restrict__ Apow,
                                                 const float2* __restrict__ prevs,
                                                 const float* __restrict__ u,
                                                 const float* __restrict__ Cre,
                                                 const float* __restrict__ Cim,
                                                 const float* __restrict__ D,
                                                 const float* __restrict__ bias,
                                                 float* __restrict__ y) {
    __shared__ float2 sx[TT3][N];                        // 32 KB, corrected x
    __shared__ __align__(16) float su[INF * SUP];        // 10 KB, u transposed [k][t]
    int b = blockIdx.y;
    int t0 = blockIdx.x * TT3;
    int tid = threadIdx.x;

    // stage corrected x-tile: x = xl + A^(j+1) * carry  (coalesced b64 loads)
#pragma unroll
    for (int i = 0; i < (TT3 * N) / 256; ++i) {
        int idx = tid + i * 256;
        int tt = idx >> 8;          // N = 256
        int n = idx & (N - 1);
        int t = t0 + tt;
        int j = t & (L - 1);
        int c = t >> LOG2L;
        float2 xv = xbuf[((size_t)b * T + t) * N + n];
        float2 p = Apow[j * N + n];
        float2 v = prevs[((size_t)b * NC + c) * N + n];
        sx[tt][n] = make_float2(xv.x + p.x * v.x - p.y * v.y,
                                xv.y + p.x * v.y + p.y * v.x);
    }
    // stage u transposed [k][t]
#pragma unroll
    for (int i = 0; i < (TT3 * INF) / 256; ++i) {
        int idx = tid + i * 256;
        int tt = idx >> 7;          // INF = 128
        int k = idx & (INF - 1);
        su[k * SUP + tt] = u[((size_t)b * T + t0 + tt) * INF + k];
    }
    __syncthreads();

    int og = tid & 63;              // output pair: o = og*2, og*2+1
    int tg = tid >> 6;              // 0..3, wave-uniform: 4 timesteps each
    const float2* C_re = (const float2*)Cre;
    const float2* C_im = (const float2*)Cim;
    const float2* D2   = (const float2*)D;
    const float2* bi2  = (const float2*)bias;

    float2 bv = bi2[og];
    float2 acc[4];
#pragma unroll
    for (int r = 0; r < 4; ++r) acc[r] = bv;

    // C-part per n: 2 coalesced global b64 (C) + 4 LDS b64 broadcasts + 16 fmaf
#pragma unroll 4
    for (int n = 0; n < N; ++n) {
        float2 cre = C_re[n * (OUTF / 2) + og];
        float2 cim = C_im[n * (OUTF / 2) + og];
#pragma unroll
        for (int r = 0; r < 4; ++r) {
            float2 xv = sx[tg * 4 + r][n];     // all-lane broadcast
            acc[r].x = fmaf(xv.x, cre.x, fmaf(-xv.y, cim.x, acc[r].x));
            acc[r].y = fmaf(xv.x, cre.y, fmaf(-xv.y, cim.y, acc[r].y));
        }
    }
    // D-part per k: 1 global b64 (D) + 1 LDS b128 broadcast (u, 4 t) + 8 fmaf
#pragma unroll 2
    for (int k = 0; k < INF; ++k) {
        float2 dv = D2[k * (OUTF / 2) + og];
        float4 uq = *(const float4*)&su[k * SUP + tg * 4];
        acc[0].x = fmaf(uq.x, dv.x, acc[0].x);  acc[0].y = fmaf(uq.x, dv.y, acc[0].y);
        acc[1].x = fmaf(uq.y, dv.x, acc[1].x);  acc[1].y = fmaf(uq.y, dv.y, acc[1].y);
        acc[2].x = fmaf(uq.z, dv.x, acc[2].x);  acc[2].y = fmaf(uq.z, dv.y, acc[2].y);
        acc[3].x = fmaf(uq.w, dv.x, acc[3].x);  acc[3].y = fmaf(uq.w, dv.y, acc[3].y);
    }
#pragma unroll
    for (int r = 0; r < 4; ++r) {
        *(float2*)&y[((size_t)b * T + t0 + tg * 4 + r) * OUTF + og * 2] = acc[r];
    }
}

extern "C" void kernel_launch(void* const* d_in, const int* in_sizes, int n_in,
                              void* d_out, int out_size, void* d_ws, size_t ws_size,
                              hipStream_t stream) {
    const float* u    = (const float*)d_in[0];
    const float* x0re = (const float*)d_in[1];
    const float* x0im = (const float*)d_in[2];
    const float* Are  = (const float*)d_in[3];
    const float* Aim  = (const float*)d_in[4];
    const float* Bre  = (const float*)d_in[5];
    const float* Bim  = (const float*)d_in[6];
    const float* Cre  = (const float*)d_in[7];
    const float* Cim  = (const float*)d_in[8];
    const float* D    = (const float*)d_in[9];
    const float* bias = (const float*)d_in[10];
    float* y = (float*)d_out;

    char* ws = (char*)d_ws;
    float2* Apow = (float2*)ws;                                   // 32 KB
    char* p = ws + (size_t)L * N * sizeof(float2);
    float2* xbuf = (float2*)p;                                    // 33.5 MB
    p += (size_t)BATCH * T * N * sizeof(float2);
    float2* carr = (float2*)p;                                    // 2 MB (finals -> prevs in-place)

    const int ysz = BATCH * T * OUTF;
    const int tail_elems = out_size - ysz;
    int tail_mode = (tail_elems >= BATCH * N * 2) ? 2
                  : (tail_elems >= BATCH * N) ? 1 : 0;
    float* tail = y + ysz;

    k0_powers<<<1, N, 0, stream>>>(Are, Aim, Apow);
    k1_scan<<<dim3(NC, BATCH), 256, 0, stream>>>(u, Bre, Bim, Apow, xbuf, carr);
    k2_carry<<<BATCH, 256, 0, stream>>>(x0re, x0im, Apow, carr, tail, tail_mode);
    k3_out<<<dim3(T / TT3, BATCH), 256, 0, stream>>>(xbuf, Apow, carr, u, Cre, Cim, D, bias, y);
}

// Round 6
// 89.943 us; speedup vs baseline: 3.2841x; 1.5857x over previous
//
#include <hip/hip_runtime.h>
#include <math.h>

#define BATCH 8
#define T 2048
#define N 256        // STATE
#define INF 128      // IN
#define OUTF 128     // OUT
#define L 16         // chunk length
#define LOG2L 4
#define NC (T / L)   // 128 chunks
#define TJ 8         // time tile in K1
#define KTOT 640     // K = 256 (Xr) + 256 (Xi) + 128 (u)
#define NKS 20       // KTOT / 32
#define ASTRIDE 40   // padded LDS row stride for A-tile, in bf16 elems (80 B)

typedef __attribute__((ext_vector_type(8))) short short8;
typedef __attribute__((ext_vector_type(4))) float f32x4;

__device__ __forceinline__ unsigned short f2b(float f) {   // fp32 -> bf16 RTNE
    union { float f; unsigned u; } x; x.f = f;
    unsigned r = (x.u + 0x7FFFu + ((x.u >> 16) & 1u)) >> 16;
    return (unsigned short)r;
}
__device__ __forceinline__ float b2f(unsigned short s) {
    union { unsigned u; float f; } x; x.u = ((unsigned)s) << 16;
    return x.f;
}

// ---------------- K0: stabilize A and build power table A^1..A^L ----------------
__global__ __launch_bounds__(N) void k0_powers(const float* __restrict__ Are,
                                               const float* __restrict__ Aim,
                                               float2* __restrict__ Apow) {
    int n = threadIdx.x;
    float ar = Are[n], ai = Aim[n];
    float m = ar * ar + ai * ai + 1.0f;
    float inv = 1.0f / sqrtf(m);
    ar *= inv; ai *= inv;
    float pr = ar, pi = ai;
    for (int j = 0; j < L; ++j) {
        Apow[j * N + n] = make_float2(pr, pi);   // A^(j+1)
        float nr = pr * ar - pi * ai;
        float ni = pr * ai + pi * ar;
        pr = nr; pi = ni;
    }
}

// ---------------- KB: build pre-swizzled bf16 B-hat fragments ----------------
// B-hat[k][o]: k<256 Cre[k][o]; k<512 -Cim[k-256][o]; else D[k-512][o]
// Fragment for mfma_f32_16x16x32_bf16 B-operand: lane l holds (k = ks*32+(l>>4)*8+j, o = ot*16+(l&15))
// grid NKS*8 blocks of 64: block = ks*8 + ot
__global__ __launch_bounds__(64) void kB_prep(const float* __restrict__ Cre,
                                              const float* __restrict__ Cim,
                                              const float* __restrict__ D,
                                              unsigned short* __restrict__ Bswz) {
    int blk = blockIdx.x;
    int ks = blk >> 3, ot = blk & 7;
    int l = threadIdx.x;
    int o = ot * 16 + (l & 15);
    int k0 = ks * 32 + (l >> 4) * 8;
    short8 out;
#pragma unroll
    for (int j = 0; j < 8; ++j) {
        int gk = k0 + j;
        float v = (gk < 256) ? Cre[gk * OUTF + o]
                : (gk < 512) ? -Cim[(gk - 256) * OUTF + o]
                             : D[(gk - 512) * OUTF + o];
        out[j] = (short)f2b(v);
    }
    *(short8*)(Bswz + ((size_t)blk * 64 + l) * 8) = out;
}

// ---------------- K1: fused u@B + chunk-local scan (writes bf16 split re/im) ----------------
// grid (NC, BATCH), block 256 (one thread per state n)
__global__ __launch_bounds__(256, 4) void k1_scan(const float* __restrict__ u,
                                                  const float* __restrict__ Bre,
                                                  const float* __restrict__ Bim,
                                                  const float2* __restrict__ Apow,
                                                  unsigned short* __restrict__ xbb,
                                                  float2* __restrict__ finals) {
    __shared__ float su[L * INF];   // 8 KB
    int c = blockIdx.x, b = blockIdx.y;
    int tid = threadIdx.x;
    const float4* ub4 = (const float4*)(u + ((size_t)b * T + (size_t)c * L) * INF);
    float4* su4 = (float4*)su;
    for (int idx = tid; idx < (L * INF) / 4; idx += 256) su4[idx] = ub4[idx];
    __syncthreads();

    int n = tid;
    float2 a = Apow[n];  // A^1 (stabilized)
    float xr = 0.f, xi = 0.f;

    for (int jt = 0; jt < L; jt += TJ) {
        float ubr[TJ], ubi[TJ];
#pragma unroll
        for (int jj = 0; jj < TJ; ++jj) { ubr[jj] = 0.f; ubi[jj] = 0.f; }
#pragma unroll 2
        for (int k = 0; k < INF; k += 2) {
            float br0 = Bre[k * N + n];
            float bi0 = Bim[k * N + n];
            float br1 = Bre[(k + 1) * N + n];
            float bi1 = Bim[(k + 1) * N + n];
#pragma unroll
            for (int jj = 0; jj < TJ; ++jj) {
                float2 uv = *(const float2*)&su[(jt + jj) * INF + k];  // broadcast b64
                ubr[jj] = fmaf(uv.x, br0, ubr[jj]);
                ubi[jj] = fmaf(uv.x, bi0, ubi[jj]);
                ubr[jj] = fmaf(uv.y, br1, ubr[jj]);
                ubi[jj] = fmaf(uv.y, bi1, ubi[jj]);
            }
        }
#pragma unroll
        for (int jj = 0; jj < TJ; ++jj) {
            float nr = a.x * xr - a.y * xi + ubr[jj];
            float ni = a.x * xi + a.y * xr + ubi[jj];
            xr = nr; xi = ni;
            size_t rowg = (size_t)b * T + (size_t)c * L + jt + jj;
            xbb[rowg * 512 + n]       = f2b(xr);
            xbb[rowg * 512 + 256 + n] = f2b(xi);
        }
    }
    finals[((size_t)b * NC + c) * N + n] = make_float2(xr, xi);
}

// ---------------- K2: carry propagation (in-place: finals -> prevs) + x_last ----------------
__global__ __launch_bounds__(256) void k2_carry(const float* __restrict__ x0re,
                                                const float* __restrict__ x0im,
                                                const float2* __restrict__ Apow,
                                                float2* __restrict__ carr,
                                                float* __restrict__ out_tail,
                                                int tail_mode) {
    int b = blockIdx.x, n = threadIdx.x;
    float pr = x0re[b * N + n], pi = x0im[b * N + n];   // x[-1] = x0
    float2 aL = Apow[(L - 1) * N + n];                   // A^L
#pragma unroll 8
    for (int c = 0; c < NC; ++c) {
        size_t off = ((size_t)b * NC + c) * N + n;
        float2 f = carr[off];                 // chunk-final
        carr[off] = make_float2(pr, pi);      // carry-in for chunk c
        float nr = f.x + aL.x * pr - aL.y * pi;
        float ni = f.y + aL.x * pi + aL.y * pr;
        pr = nr; pi = ni;
    }
    if (tail_mode == 2) {
        out_tail[(b * N + n) * 2 + 0] = pr;
        out_tail[(b * N + n) * 2 + 1] = pi;
    } else if (tail_mode == 1) {
        out_tail[b * N + n] = pr;
    }
}

// ---------------- K3: bf16 MFMA GEMM  y = A-hat @ B-hat + bias ----------------
// A-hat row rowg: [Xr_corr(256) | Xi_corr(256) | u(128)] built on the fly per K-step.
// grid 256 blocks (64 rows each), block 256 = 4 waves; wave w: rows w*16..w*16+15, all 128 cols.
__global__ __launch_bounds__(256) void k3_mfma(const unsigned short* __restrict__ xbb,
                                               const float2* __restrict__ Apow,
                                               const float2* __restrict__ carr,
                                               const float* __restrict__ u,
                                               const unsigned short* __restrict__ Bswz,
                                               const float* __restrict__ bias,
                                               float* __restrict__ y) {
    __shared__ unsigned short As[64 * ASTRIDE];   // 5 KB, 80B rows -> 2-way banks (free)
    int tid = threadIdx.x;
    int lane = tid & 63;
    int w = tid >> 6;

    // staging role: thread stages 8 bf16 at (srow, kq..kq+7)
    int srow = tid >> 2;
    int kq = (tid & 3) * 8;
    size_t rowg = (size_t)blockIdx.x * 64 + srow;
    int b = (int)(rowg >> 11);
    int t = (int)(rowg & 2047);
    int jrow = t & (L - 1);
    int crow = t >> LOG2L;
    const float4* Ap4 = (const float4*)Apow;
    const float4* Cv4 = (const float4*)carr;
    size_t apbase = ((size_t)jrow * N) >> 1;                 // float4 index
    size_t cvbase = (((size_t)b * NC + crow) * N) >> 1;

    f32x4 acc[8];
#pragma unroll
    for (int ot = 0; ot < 8; ++ot) acc[ot] = (f32x4){0.f, 0.f, 0.f, 0.f};

    float4 pa[4], pv[4], pu0, pu1;
    short8 pxb;

    auto LOAD = [&](int ks) {
        if (ks < 16) {
            int n0 = (ks & 7) * 32 + kq;
            int col0 = ((ks < 8) ? 0 : 256) + n0;
            pxb = *(const short8*)(xbb + rowg * 512 + col0);
#pragma unroll
            for (int q = 0; q < 4; ++q) {
                pa[q] = Ap4[apbase + (n0 >> 1) + q];
                pv[q] = Cv4[cvbase + (n0 >> 1) + q];
            }
        } else {
            const float4* up = (const float4*)(u + rowg * INF + (ks - 16) * 32 + kq);
            pu0 = up[0]; pu1 = up[1];
        }
    };
    auto WRITE = [&](int ks) {
        short8 st;
        if (ks < 16) {
#pragma unroll
            for (int j = 0; j < 8; ++j) {
                float xv = b2f((unsigned short)pxb[j]);
                float4 aq = pa[j >> 1];
                float4 vq = pv[j >> 1];
                float px = (j & 1) ? aq.z : aq.x;
                float py = (j & 1) ? aq.w : aq.y;
                float vx = (j & 1) ? vq.z : vq.x;
                float vy = (j & 1) ? vq.w : vq.y;
                float corr = (ks < 8) ? (px * vx - py * vy) : (px * vy + py * vx);
                st[j] = (short)f2b(xv + corr);
            }
        } else {
#pragma unroll
            for (int j = 0; j < 8; ++j) {
                float uv = (j < 4) ? ((j == 0) ? pu0.x : (j == 1) ? pu0.y : (j == 2) ? pu0.z : pu0.w)
                                   : ((j == 4) ? pu1.x : (j == 5) ? pu1.y : (j == 6) ? pu1.z : pu1.w);
                st[j] = (short)f2b(uv);
            }
        }
        *(short8*)(&As[srow * ASTRIDE + kq]) = st;
    };

    const short8* Bfr = (const short8*)Bswz;
    // A-frag address: lane l -> row w*16+(l&15), k-block (l>>4)*8
    const short8* afp = (const short8*)&As[(w * 16 + (lane & 15)) * ASTRIDE + (lane >> 4) * 8];

    LOAD(0);
    for (int ks = 0; ks < NKS; ++ks) {
        WRITE(ks);
        __syncthreads();
        if (ks < NKS - 1) LOAD(ks + 1);   // overlaps with mfma below
        short8 af = *afp;
#pragma unroll
        for (int ot = 0; ot < 8; ++ot) {
            short8 bf = Bfr[((size_t)ks * 8 + ot) * 64 + lane];
            acc[ot] = __builtin_amdgcn_mfma_f32_16x16x32_bf16(af, bf, acc[ot], 0, 0, 0);
        }
        __syncthreads();
    }

    // epilogue: D layout col = lane&15, row = (lane>>4)*4 + r
    int colb = lane & 15;
    int rq = lane >> 4;
#pragma unroll
    for (int ot = 0; ot < 8; ++ot) {
        int o = ot * 16 + colb;
        float bv = bias[o];
#pragma unroll
        for (int r = 0; r < 4; ++r) {
            int row = w * 16 + rq * 4 + r;
            y[((size_t)blockIdx.x * 64 + row) * OUTF + o] = acc[ot][r] + bv;
        }
    }
}

extern "C" void kernel_launch(void* const* d_in, const int* in_sizes, int n_in,
                              void* d_out, int out_size, void* d_ws, size_t ws_size,
                              hipStream_t stream) {
    const float* u    = (const float*)d_in[0];
    const float* x0re = (const float*)d_in[1];
    const float* x0im = (const float*)d_in[2];
    const float* Are  = (const float*)d_in[3];
    const float* Aim  = (const float*)d_in[4];
    const float* Bre  = (const float*)d_in[5];
    const float* Bim  = (const float*)d_in[6];
    const float* Cre  = (const float*)d_in[7];
    const float* Cim  = (const float*)d_in[8];
    const float* D    = (const float*)d_in[9];
    const float* bias = (const float*)d_in[10];
    float* y = (float*)d_out;

    char* ws = (char*)d_ws;
    float2* Apow = (float2*)ws;                                    // 32 KB
    char* p = ws + (size_t)L * N * sizeof(float2);
    float2* carr = (float2*)p;                                     // 2 MB
    p += (size_t)BATCH * NC * N * sizeof(float2);
    unsigned short* xbb = (unsigned short*)p;                      // 16 MB bf16 [row][re256|im256]
    p += (size_t)BATCH * T * 512 * sizeof(unsigned short);
    unsigned short* Bswz = (unsigned short*)p;                     // 160 KB

    const int ysz = BATCH * T * OUTF;
    const int tail_elems = out_size - ysz;
    int tail_mode = (tail_elems >= BATCH * N * 2) ? 2
                  : (tail_elems >= BATCH * N) ? 1 : 0;
    float* tail = y + ysz;

    k0_powers<<<1, N, 0, stream>>>(Are, Aim, Apow);
    kB_prep<<<NKS * 8, 64, 0, stream>>>(Cre, Cim, D, Bswz);
    k1_scan<<<dim3(NC, BATCH), 256, 0, stream>>>(u, Bre, Bim, Apow, xbb, carr);
    k2_carry<<<BATCH, 256, 0, stream>>>(x0re, x0im, Apow, carr, tail, tail_mode);
    k3_mfma<<<(BATCH * T) / 64, 256, 0, stream>>>(xbb, Apow, carr, u, Bswz, bias, y);
}

// Round 7
// 61.061 us; speedup vs baseline: 4.8375x; 1.4730x over previous
//
#include <hip/hip_runtime.h>
#include <math.h>

#define BATCH 8
#define T 2048
#define N 256        // STATE
#define INF 128      // IN
#define OUTF 128     // OUT
#define L 16         // chunk length
#define LOG2L 4
#define NC (T / L)   // 128 chunks
#define KTOT 640     // K for k3 = 256 (Xr) + 256 (Xi) + 128 (u)
#define NKS 20       // KTOT / 32  (C-hat K-steps)
#define NKU 4        // INF / 32   (Bh K-steps)
#define ASTRIDE 40   // padded LDS row stride for k3 A-tile, bf16 elems
#define UBS 516      // padded fp32 col-stride for kU uB tile

typedef __attribute__((ext_vector_type(8))) short short8;
typedef __attribute__((ext_vector_type(4))) float f32x4;

__device__ __forceinline__ unsigned short f2b(float f) {   // fp32 -> bf16 RTNE
    union { float f; unsigned u; } x; x.f = f;
    unsigned r = (x.u + 0x7FFFu + ((x.u >> 16) & 1u)) >> 16;
    return (unsigned short)r;
}
__device__ __forceinline__ float b2f(unsigned short s) {
    union { unsigned u; float f; } x; x.u = ((unsigned)s) << 16;
    return x.f;
}

// ---------------- K_PREP: Apow + C-hat frags (Bswz) + Bh frags (Bswz2) ----------------
// blocks 0..39   : C-hat fragments, 4 units/block (unit = ks*8+ot, 160 units)
// blocks 40..71  : Bh fragments,    4 units/block (unit = ks*32+ct, 128 units)
// block  72      : Apow (A stabilization + powers)
__global__ __launch_bounds__(256) void k_prep(const float* __restrict__ Are,
                                              const float* __restrict__ Aim,
                                              const float* __restrict__ Bre,
                                              const float* __restrict__ Bim,
                                              const float* __restrict__ Cre,
                                              const float* __restrict__ Cim,
                                              const float* __restrict__ D,
                                              float2* __restrict__ Apow,
                                              unsigned short* __restrict__ Bswz,
                                              unsigned short* __restrict__ Bswz2) {
    int blk = blockIdx.x;
    int tid = threadIdx.x;
    if (blk < 40) {
        int unit = blk * 4 + (tid >> 6);     // 0..159
        int ks = unit >> 3, ot = unit & 7;
        int l = tid & 63;
        int o = ot * 16 + (l & 15);
        int k0 = ks * 32 + (l >> 4) * 8;
        short8 out;
#pragma unroll
        for (int j = 0; j < 8; ++j) {
            int gk = k0 + j;
            float v = (gk < 256) ? Cre[gk * OUTF + o]
                    : (gk < 512) ? -Cim[(gk - 256) * OUTF + o]
                                 : D[(gk - 512) * OUTF + o];
            out[j] = (short)f2b(v);
        }
        *(short8*)(Bswz + ((size_t)unit * 64 + l) * 8) = out;
    } else if (blk < 72) {
        int unit = (blk - 40) * 4 + (tid >> 6);   // 0..127
        int l = tid & 63;
        int col = (unit & 31) * 16 + (l & 15);
        int k0 = (unit >> 5) * 32 + (l >> 4) * 8;
        short8 out;
#pragma unroll
        for (int j = 0; j < 8; ++j) {
            int gk = k0 + j;
            float v = (col < 256) ? Bre[gk * N + col] : Bim[gk * N + col - 256];
            out[j] = (short)f2b(v);
        }
        *(short8*)(Bswz2 + ((size_t)unit * 64 + l) * 8) = out;
    } else {
        int n = tid;
        float ar = Are[n], ai = Aim[n];
        float inv = 1.0f / sqrtf(ar * ar + ai * ai + 1.0f);
        ar *= inv; ai *= inv;
        float pr = ar, pi = ai;
        for (int j = 0; j < L; ++j) {
            Apow[j * N + n] = make_float2(pr, pi);   // A^(j+1)
            float nr = pr * ar - pi * ai;
            float ni = pr * ai + pi * ar;
            pr = nr; pi = ni;
        }
    }
}

// ---------------- KU: uB = u @ Bh via MFMA, then chunk-local scan ----------------
// grid 512 blocks x 512 threads (8 waves). Block = 32 rows (2 chunks) x 512 cols.
// wave w: row-group rg=w>>2 (16 rows), col-quarter cq=w&3 (8 col-tiles).
__global__ __launch_bounds__(512, 2) void kU_scan(const float* __restrict__ u,
                                                  const unsigned short* __restrict__ Bswz2,
                                                  const float2* __restrict__ Apow,
                                                  unsigned short* __restrict__ xbb,
                                                  float2* __restrict__ carr) {
    __shared__ float uB[32][UBS];      // 64.5 KB
    int tid = threadIdx.x;
    int lane = tid & 63;
    int w = tid >> 6;
    int rg = w >> 2;
    int cq = w & 3;
    size_t row0 = (size_t)blockIdx.x * 32;
    const float* uprow = u + (row0 + rg * 16 + (lane & 15)) * INF + (lane >> 4) * 8;

    f32x4 acc[8];
#pragma unroll
    for (int i = 0; i < 8; ++i) acc[i] = (f32x4){0.f, 0.f, 0.f, 0.f};

    const short8* Bfr2 = (const short8*)Bswz2;
#pragma unroll
    for (int ks = 0; ks < NKU; ++ks) {
        float4 a0 = *(const float4*)(uprow + ks * 32);
        float4 a1 = *(const float4*)(uprow + ks * 32 + 4);
        short8 af;
        af[0] = (short)f2b(a0.x); af[1] = (short)f2b(a0.y);
        af[2] = (short)f2b(a0.z); af[3] = (short)f2b(a0.w);
        af[4] = (short)f2b(a1.x); af[5] = (short)f2b(a1.y);
        af[6] = (short)f2b(a1.z); af[7] = (short)f2b(a1.w);
#pragma unroll
        for (int i = 0; i < 8; ++i) {
            int ct = cq * 8 + i;
            short8 bf = Bfr2[(size_t)(ks * 32 + ct) * 64 + lane];
            acc[i] = __builtin_amdgcn_mfma_f32_16x16x32_bf16(af, bf, acc[i], 0, 0, 0);
        }
    }
    // spill acc -> LDS (C/D layout: col = lane&15, row = (lane>>4)*4 + r)
    {
        int rbase = rg * 16 + (lane >> 4) * 4;
        int cb = lane & 15;
#pragma unroll
        for (int i = 0; i < 8; ++i) {
            int col = (cq * 8 + i) * 16 + cb;
#pragma unroll
            for (int r = 0; r < 4; ++r)
                uB[rbase + r][col] = acc[i][r];
        }
    }
    __syncthreads();

    // scan: thread -> chunk ch = tid>>8 (0..1), state n = tid&255
    int ch = tid >> 8;
    int n = tid & 255;
    size_t rowg0 = row0 + ch * 16;
    int b = (int)(rowg0 >> 11);
    int c = (int)((rowg0 & 2047) >> LOG2L);
    float2 a = Apow[n];          // A^1
    float xr = 0.f, xi = 0.f;
#pragma unroll
    for (int j = 0; j < 16; ++j) {
        float ur = uB[ch * 16 + j][n];
        float ui = uB[ch * 16 + j][256 + n];
        float nr = fmaf(a.x, xr, fmaf(-a.y, xi, ur));
        float ni = fmaf(a.x, xi, fmaf(a.y, xr, ui));
        xr = nr; xi = ni;
        size_t rowg = rowg0 + j;
        xbb[rowg * 512 + n]       = f2b(xr);
        xbb[rowg * 512 + 256 + n] = f2b(xi);
    }
    carr[((size_t)b * NC + c) * N + n] = make_float2(xr, xi);
}

// ---------------- K2: carry propagation (in-place: finals -> prevs) + x_last ----------------
__global__ __launch_bounds__(256) void k2_carry(const float* __restrict__ x0re,
                                                const float* __restrict__ x0im,
                                                const float2* __restrict__ Apow,
                                                float2* __restrict__ carr,
                                                float* __restrict__ out_tail,
                                                int tail_mode) {
    int b = blockIdx.x, n = threadIdx.x;
    float pr = x0re[b * N + n], pi = x0im[b * N + n];   // x[-1] = x0
    float2 aL = Apow[(L - 1) * N + n];                   // A^L
#pragma unroll 8
    for (int c = 0; c < NC; ++c) {
        size_t off = ((size_t)b * NC + c) * N + n;
        float2 f = carr[off];                 // chunk-final
        carr[off] = make_float2(pr, pi);      // carry-in for chunk c
        float nr = f.x + aL.x * pr - aL.y * pi;
        float ni = f.y + aL.x * pi + aL.y * pr;
        pr = nr; pi = ni;
    }
    if (tail_mode == 2) {
        out_tail[(b * N + n) * 2 + 0] = pr;
        out_tail[(b * N + n) * 2 + 1] = pi;
    } else if (tail_mode == 1) {
        out_tail[b * N + n] = pr;
    }
}

// ---------------- K3: bf16 MFMA GEMM  y = A-hat @ B-hat + bias ----------------
// A-hat row: [Xr_corr(256) | Xi_corr(256) | u(128)] built on the fly per K-step.
__global__ __launch_bounds__(256) void k3_mfma(const unsigned short* __restrict__ xbb,
                                               const float2* __restrict__ Apow,
                                               const float2* __restrict__ carr,
                                               const float* __restrict__ u,
                                               const unsigned short* __restrict__ Bswz,
                                               const float* __restrict__ bias,
                                               float* __restrict__ y) {
    __shared__ unsigned short As[64 * ASTRIDE];   // 5 KB
    int tid = threadIdx.x;
    int lane = tid & 63;
    int w = tid >> 6;

    int srow = tid >> 2;
    int kq = (tid & 3) * 8;
    size_t rowg = (size_t)blockIdx.x * 64 + srow;
    int b = (int)(rowg >> 11);
    int t = (int)(rowg & 2047);
    int jrow = t & (L - 1);
    int crow = t >> LOG2L;
    const float4* Ap4 = (const float4*)Apow;
    const float4* Cv4 = (const float4*)carr;
    size_t apbase = ((size_t)jrow * N) >> 1;
    size_t cvbase = (((size_t)b * NC + crow) * N) >> 1;

    f32x4 acc[8];
#pragma unroll
    for (int ot = 0; ot < 8; ++ot) acc[ot] = (f32x4){0.f, 0.f, 0.f, 0.f};

    float4 pa[4], pv[4], pu0, pu1;
    short8 pxb;

    auto LOAD = [&](int ks) {
        if (ks < 16) {
            int n0 = (ks & 7) * 32 + kq;
            int col0 = ((ks < 8) ? 0 : 256) + n0;
            pxb = *(const short8*)(xbb + rowg * 512 + col0);
#pragma unroll
            for (int q = 0; q < 4; ++q) {
                pa[q] = Ap4[apbase + (n0 >> 1) + q];
                pv[q] = Cv4[cvbase + (n0 >> 1) + q];
            }
        } else {
            const float4* up = (const float4*)(u + rowg * INF + (ks - 16) * 32 + kq);
            pu0 = up[0]; pu1 = up[1];
        }
    };
    auto WRITE = [&](int ks) {
        short8 st;
        if (ks < 16) {
#pragma unroll
            for (int j = 0; j < 8; ++j) {
                float xv = b2f((unsigned short)pxb[j]);
                float4 aq = pa[j >> 1];
                float4 vq = pv[j >> 1];
                float px = (j & 1) ? aq.z : aq.x;
                float py = (j & 1) ? aq.w : aq.y;
                float vx = (j & 1) ? vq.z : vq.x;
                float vy = (j & 1) ? vq.w : vq.y;
                float corr = (ks < 8) ? (px * vx - py * vy) : (px * vy + py * vx);
                st[j] = (short)f2b(xv + corr);
            }
        } else {
#pragma unroll
            for (int j = 0; j < 8; ++j) {
                float uv = (j < 4) ? ((j == 0) ? pu0.x : (j == 1) ? pu0.y : (j == 2) ? pu0.z : pu0.w)
                                   : ((j == 4) ? pu1.x : (j == 5) ? pu1.y : (j == 6) ? pu1.z : pu1.w);
                st[j] = (short)f2b(uv);
            }
        }
        *(short8*)(&As[srow * ASTRIDE + kq]) = st;
    };

    const short8* Bfr = (const short8*)Bswz;
    const short8* afp = (const short8*)&As[(w * 16 + (lane & 15)) * ASTRIDE + (lane >> 4) * 8];

    LOAD(0);
    for (int ks = 0; ks < NKS; ++ks) {
        WRITE(ks);
        __syncthreads();
        if (ks < NKS - 1) LOAD(ks + 1);
        short8 af = *afp;
#pragma unroll
        for (int ot = 0; ot < 8; ++ot) {
            short8 bf = Bfr[((size_t)ks * 8 + ot) * 64 + lane];
            acc[ot] = __builtin_amdgcn_mfma_f32_16x16x32_bf16(af, bf, acc[ot], 0, 0, 0);
        }
        __syncthreads();
    }

    int colb = lane & 15;
    int rq = lane >> 4;
#pragma unroll
    for (int ot = 0; ot < 8; ++ot) {
        int o = ot * 16 + colb;
        float bv = bias[o];
#pragma unroll
        for (int r = 0; r < 4; ++r) {
            int row = w * 16 + rq * 4 + r;
            y[((size_t)blockIdx.x * 64 + row) * OUTF + o] = acc[ot][r] + bv;
        }
    }
}

extern "C" void kernel_launch(void* const* d_in, const int* in_sizes, int n_in,
                              void* d_out, int out_size, void* d_ws, size_t ws_size,
                              hipStream_t stream) {
    const float* u    = (const float*)d_in[0];
    const float* x0re = (const float*)d_in[1];
    const float* x0im = (const float*)d_in[2];
    const float* Are  = (const float*)d_in[3];
    const float* Aim  = (const float*)d_in[4];
    const float* Bre  = (const float*)d_in[5];
    const float* Bim  = (const float*)d_in[6];
    const float* Cre  = (const float*)d_in[7];
    const float* Cim  = (const float*)d_in[8];
    const float* D    = (const float*)d_in[9];
    const float* bias = (const float*)d_in[10];
    float* y = (float*)d_out;

    char* ws = (char*)d_ws;
    float2* Apow = (float2*)ws;                                    // 32 KB
    char* p = ws + (size_t)L * N * sizeof(float2);
    float2* carr = (float2*)p;                                     // 2 MB
    p += (size_t)BATCH * NC * N * sizeof(float2);
    unsigned short* xbb = (unsigned short*)p;                      // 16 MB bf16 [row][re256|im256]
    p += (size_t)BATCH * T * 512 * sizeof(unsigned short);
    unsigned short* Bswz = (unsigned short*)p;                     // 160 KB (C-hat frags)
    p += (size_t)NKS * 8 * 64 * 8 * sizeof(unsigned short);
    unsigned short* Bswz2 = (unsigned short*)p;                    // 128 KB (Bh frags)

    const int ysz = BATCH * T * OUTF;
    const int tail_elems = out_size - ysz;
    int tail_mode = (tail_elems >= BATCH * N * 2) ? 2
                  : (tail_elems >= BATCH * N) ? 1 : 0;
    float* tail = y + ysz;

    k_prep<<<73, 256, 0, stream>>>(Are, Aim, Bre, Bim, Cre, Cim, D, Apow, Bswz, Bswz2);
    kU_scan<<<(BATCH * T) / 32, 512, 0, stream>>>(u, Bswz2, Apow, xbb, carr);
    k2_carry<<<BATCH, 256, 0, stream>>>(x0re, x0im, Apow, carr, tail, tail_mode);
    k3_mfma<<<(BATCH * T) / 64, 256, 0, stream>>>(xbb, Apow, carr, u, Bswz, bias, y);
}